// Round 5
// baseline (186.453 us; speedup 1.0000x reference)
//
#include <hip/hip_runtime.h>
#include <math.h>
#include <stdint.h>

#define BB 4
#define NN 1024
#define HH 8
#define DD 64
#define BS 32
#define NB 32   // NN/BS
#define SS 16   // BLOCK_COUNTS
#define NT 128  // tiles per head-queue (BB*NB)

typedef __attribute__((ext_vector_type(8)))  short bf16x8;
typedef __attribute__((ext_vector_type(16))) float f32x16;
typedef __attribute__((ext_vector_type(2)))  int   int2v;

union FragU { bf16x8 h; uint32_t u[4]; };

struct KVBuf {
    FragU k0, k1, k2, k3;     // K fragments t=0..3
    FragU v00, v10, v01, v11; // V fragments [s][dh]
};

#define ZERO16 {0.f,0.f,0.f,0.f,0.f,0.f,0.f,0.f,0.f,0.f,0.f,0.f,0.f,0.f,0.f,0.f}

__device__ __forceinline__ uint32_t cvt_pk_bf16(float lo, float hi) {
    uint32_t r;
    asm("v_cvt_pk_bf16_f32 %0, %1, %2" : "=v"(r) : "v"(lo), "v"(hi));
    return r;
}

__device__ __forceinline__ uint16_t bf16_rne(float x) {
    uint32_t fb = __float_as_uint(x);
    return (uint16_t)((fb + 0x7fffu + ((fb >> 16) & 1u)) >> 16);
}

__device__ __forceinline__ float silu_f(float x) {
    return __fdividef(x, 1.f + __expf(-x));
}

// Prepass: one block per (b,h,cmp-block of 32 tokens).
//  Kb : bf16 [b][h][n][d]   K * 0.125 (exact pow2 pre-scale)
//  Vt : bf16 [b][h][d][n]   transposed V
//  kc : f32  [b][h][blk][d] block-mean K * 0.125 (f32-exact selection)
//  vct: bf16 [b][h][d][blk] block-mean V, transposed
//  cnt: 8 per-head queue counters (zeroed here, block 0)
__global__ __launch_bounds__(256) void prep_kernel(
    const float* __restrict__ pk, const float* __restrict__ pv,
    uint16_t* __restrict__ Kb, uint16_t* __restrict__ Vt,
    float* __restrict__ kc, uint16_t* __restrict__ vct,
    int* __restrict__ cnt)
{
    __shared__ float klds[32][65];
    __shared__ float vlds[32][65];
    const int t = threadIdx.x;
    if (blockIdx.x == 0 && t < 8) cnt[t] = 0;
    const int blk = blockIdx.x & 31;
    const int h = (blockIdx.x >> 5) & 7;
    const int b = blockIdx.x >> 8;
    const int bh = b * 8 + h;

    const int r = t >> 3;            // token row 0..31
    const int dg = (t & 7) * 8;      // d group
    size_t sbase = (((size_t)(b * NN + blk * BS + r)) * HH + h) * DD + dg;
    float4 ka = *(const float4*)(pk + sbase);
    float4 kb4 = *(const float4*)(pk + sbase + 4);
    float4 va = *(const float4*)(pv + sbase);
    float4 vb4 = *(const float4*)(pv + sbase + 4);

    FragU kf;   // pre-scaled by 0.125 (exact)
    kf.u[0] = cvt_pk_bf16(ka.x * 0.125f, ka.y * 0.125f);
    kf.u[1] = cvt_pk_bf16(ka.z * 0.125f, ka.w * 0.125f);
    kf.u[2] = cvt_pk_bf16(kb4.x * 0.125f, kb4.y * 0.125f);
    kf.u[3] = cvt_pk_bf16(kb4.z * 0.125f, kb4.w * 0.125f);
    *(bf16x8*)(Kb + (((size_t)bh * NN) + blk * BS + r) * DD + dg) = kf.h;

    *(float4*)&klds[r][dg] = ka;  *(float4*)&klds[r][dg + 4] = kb4;
    *(float4*)&vlds[r][dg] = va;  *(float4*)&vlds[r][dg + 4] = vb4;
    __syncthreads();

    if (t < 64) {                    // wave 0: kc (f32 block-mean K, pre-scaled)
        float s = 0.f;
        #pragma unroll
        for (int j = 0; j < 32; ++j) s += klds[j][t];
        kc[((size_t)bh * NB + blk) * DD + t] = s * (0.125f / BS);
    } else if (t < 128) {            // wave 1: vct (bf16 block-mean V, transposed)
        int d = t - 64;
        float s = 0.f;
        #pragma unroll
        for (int j = 0; j < 32; ++j) s += vlds[j][d];
        vct[((size_t)bh * DD + d) * NB + blk] = bf16_rne(s * (1.f / BS));
    }

    // all threads: V transpose -> Vt
    {
        int d = t >> 2, ng = (t & 3) * 8;
        float p0 = vlds[ng + 0][d], p1 = vlds[ng + 1][d];
        float p2 = vlds[ng + 2][d], p3 = vlds[ng + 3][d];
        float p4 = vlds[ng + 4][d], p5 = vlds[ng + 5][d];
        float p6 = vlds[ng + 6][d], p7 = vlds[ng + 7][d];
        FragU vf;
        vf.u[0] = cvt_pk_bf16(p0, p1); vf.u[1] = cvt_pk_bf16(p2, p3);
        vf.u[2] = cvt_pk_bf16(p4, p5); vf.u[3] = cvt_pk_bf16(p6, p7);
        *(bf16x8*)(Vt + ((size_t)bh * DD + d) * NN + blk * BS + ng) = vf.h;
    }
}

__device__ __forceinline__ void load_kv(KVBuf& bu, const uint16_t* __restrict__ Kb,
                                        const uint16_t* __restrict__ Vt,
                                        int bh, int kb, int l31, int hi)
{
    const uint16_t* krow = Kb + (((size_t)bh * NN) + kb * BS + l31) * DD + hi * 8;
    bu.k0.h = *(const bf16x8*)(krow);
    bu.k1.h = *(const bf16x8*)(krow + 16);
    bu.k2.h = *(const bf16x8*)(krow + 32);
    bu.k3.h = *(const bf16x8*)(krow + 48);
    const uint16_t* vrow = Vt + ((size_t)bh * DD + l31) * NN + kb * BS + hi * 8;
    bu.v00.h = *(const bf16x8*)(vrow);
    bu.v10.h = *(const bf16x8*)(vrow + 16);
    const uint16_t* vrow1 = vrow + 32 * NN;
    bu.v01.h = *(const bf16x8*)(vrow1);
    bu.v11.h = *(const bf16x8*)(vrow1 + 16);
}

// Persistent blocks; per-head work queue (head = bid&7 = XCD under round-robin).
__global__ __launch_bounds__(256, 3) void bsa_mfma_kernel(
    const float* __restrict__ pq, const uint16_t* __restrict__ Kb,
    const uint16_t* __restrict__ Vt, const float* __restrict__ kc,
    const uint16_t* __restrict__ vct, const float* __restrict__ gw,
    const int* __restrict__ xoff, int* __restrict__ cnt,
    float* __restrict__ out)
{
    __shared__ float qlds[32][64];
    __shared__ __align__(16) uint16_t pcmp[32][40];
    __shared__ uint32_t selmask[32];
    __shared__ float gateC[32], gateS[32];
    __shared__ float olds[32][64];
    __shared__ int tile_s;

    const int tid = threadIdx.x;
    const int lane = tid & 63;
    const int w = tid >> 6;
    const int l31 = lane & 31;
    const int hi = lane >> 5;
    const int h = blockIdx.x & 7;

    for (;;) {
        __syncthreads();
        if (tid == 0) tile_s = atomicAdd(&cnt[h], 1);
        __syncthreads();
        const int idx = tile_s;
        if (idx >= NT) break;
        const int qb = 31 - (idx >> 2);     // heavy-first
        const int b = idx & 3;
        const int bh = b * 8 + h;

        const int off0 = xoff[b];
        const int len = xoff[b + 1] - off0;
        if (qb * BS >= len) continue;       // padded tile (uniform)

        // ---- zero slab + load Q tile ----
        {
            int q = tid >> 3, d = (tid & 7) * 8;
            *(float4*)&olds[q][d] = make_float4(0.f, 0.f, 0.f, 0.f);
            *(float4*)&olds[q][d + 4] = make_float4(0.f, 0.f, 0.f, 0.f);
            const float* src = pq + (((size_t)(b * NN + qb * BS + q)) * HH + h) * DD + d;
            *(float4*)&qlds[q][d] = *(const float4*)src;
            *(float4*)&qlds[q][d + 4] = *(const float4*)(src + 4);
        }

        // ---- Q B-fragments (bf16, unscaled) ----
        FragU qf[4];
        {
            const float* qrow = pq + (((size_t)(b * NN + qb * BS + l31)) * HH + h) * DD;
            #pragma unroll
            for (int t = 0; t < 4; ++t) {
                const float* qp = qrow + t * 16 + hi * 8;
                float4 x = *(const float4*)qp;
                float4 y = *(const float4*)(qp + 4);
                qf[t].u[0] = cvt_pk_bf16(x.x, x.y);
                qf[t].u[1] = cvt_pk_bf16(x.z, x.w);
                qf[t].u[2] = cvt_pk_bf16(y.x, y.y);
                qf[t].u[3] = cvt_pk_bf16(y.z, y.w);
            }
        }

        // ---- compressed-K fragments (pre-scaled) ----
        float4 kcv[8];
        {
            const float* kcrow = kc + ((size_t)bh * NB + l31) * DD + hi * 32;
            #pragma unroll
            for (int i = 0; i < 8; ++i) kcv[i] = *(const float4*)(kcrow + i * 4);
        }

        __syncthreads();   // qlds + olds ready

        // ---- selection + gates: wave w -> queries w*8..w*8+7 ----
        for (int j = 0; j < 8; ++j) {
            int q = w * 8 + j;
            const float* qv = qlds[q];
            const float* qh = qv + hi * 32;
            float part = 0.f;
            #pragma unroll
            for (int i = 0; i < 8; ++i) {
                float4 qq = *(const float4*)(qh + i * 4);
                part += qq.x * kcv[i].x + qq.y * kcv[i].y + qq.z * kcv[i].z + qq.w * kcv[i].w;
            }
            float s = part + __shfl_xor(part, 32);       // already scaled
            float p = (l31 <= qb) ? silu_f(s) : 0.f;
            if (lane < 32) pcmp[q][l31] = bf16_rne(p);
            uint32_t m;
            if (qb >= SS) {
                float vsel = (l31 <= qb) ? s : -INFINITY;
                int rank = 0;
                #pragma unroll
                for (int off = 1; off < 32; ++off) {
                    float o = __shfl_xor(vsel, off);
                    int oi = l31 ^ off;
                    rank += (o > vsel || (o == vsel && oi < l31)) ? 1 : 0;
                }
                m = (uint32_t)(__ballot(rank < SS) & 0xffffffffu);
            } else {
                m = (1u << (qb + 1)) - 1u;
            }
            if (lane == 0) selmask[q] = m;
            float qd = qv[lane];
            float g0 = qd * gw[(h * DD + lane) * 3 + 0];
            float g1 = qd * gw[(h * DD + lane) * 3 + 1];
            #pragma unroll
            for (int off = 32; off; off >>= 1) {
                g0 += __shfl_xor(g0, off);
                g1 += __shfl_xor(g1, off);
            }
            if (lane == 0) {
                gateC[q] = __frcp_rn(1.f + __expf(-g0));
                gateS[q] = __frcp_rn(1.f + __expf(-g1));
            }
        }

        __syncthreads();   // pcmp, selmask, gates ready

        const uint32_t mymask = selmask[l31];
        uint32_t tmask = mymask;
        #pragma unroll
        for (int off = 1; off < 32; off <<= 1) tmask |= __shfl_xor(tmask, off);

        // ---- wave 3: compressed branch (gated) ----
        if (w == 3) {
            f32x16 c0 = ZERO16, c1 = ZERO16;
            #pragma unroll
            for (int s = 0; s < 2; ++s) {
                FragU pa;
                pa.h = *(const bf16x8*)&pcmp[l31][s * 16 + hi * 8];
                #pragma unroll
                for (int dh = 0; dh < 2; ++dh) {
                    FragU vb;
                    vb.h = *(const bf16x8*)(vct + ((size_t)bh * DD + dh * 32 + l31) * NB + s * 16 + hi * 8);
                    if (dh == 0) c0 = __builtin_amdgcn_mfma_f32_32x32x16_bf16(pa.h, vb.h, c0, 0, 0, 0);
                    else         c1 = __builtin_amdgcn_mfma_f32_32x32x16_bf16(pa.h, vb.h, c1, 0, 0, 0);
                }
            }
            #pragma unroll
            for (int r = 0; r < 16; ++r) {
                int q = (r & 3) + 8 * (r >> 2) + 4 * hi;
                float gc = gateC[q];
                atomicAdd(&olds[q][l31], gc * c0[r]);
                atomicAdd(&olds[q][32 + l31], gc * c1[r]);
            }
        }

        // ---- extract this wave's key-block bits (round-robin by set-bit index) ----
        uint32_t mw = 0;
        {
            uint32_t m = tmask; int c = 0;
            while (m) {
                int kb = __builtin_ctz(m); m &= m - 1;
                if (((c++) & 3) == w) mw |= (1u << kb);
            }
        }

        // ---- main loop: 2-deep register-double-buffered pipeline ----
        f32x16 accO0 = ZERO16, accO1 = ZERO16;
        const bool any = (mw != 0);
        const int qpos = qb * BS + l31;
        if (any) {
            KVBuf bufA, bufB;
            int kbA = __builtin_ctz(mw);
            uint32_t rem = mw & (mw - 1);
            load_kv(bufA, Kb, Vt, bh, kbA, l31, hi);
            for (;;) {
                const bool haveB = (rem != 0);
                int kbB = 0;
                if (haveB) {
                    kbB = __builtin_ctz(rem);
                    rem &= rem - 1;
                    load_kv(bufB, Kb, Vt, bh, kbB, l31, hi);   // prefetch next
                }
                // ---- compute current (kbA, bufA) ----
                f32x16 accS = ZERO16;
                accS = __builtin_amdgcn_mfma_f32_32x32x16_bf16(bufA.k0.h, qf[0].h, accS, 0, 0, 0);
                accS = __builtin_amdgcn_mfma_f32_32x32x16_bf16(bufA.k1.h, qf[1].h, accS, 0, 0, 0);
                accS = __builtin_amdgcn_mfma_f32_32x32x16_bf16(bufA.k2.h, qf[2].h, accS, 0, 0, 0);
                accS = __builtin_amdgcn_mfma_f32_32x32x16_bf16(bufA.k3.h, qf[3].h, accS, 0, 0, 0);
                const bool selbit = (mymask >> kbA) & 1;
                float pr[16];
                if (kbA == qb) {       // diagonal: per-token causal check
                    #pragma unroll
                    for (int r = 0; r < 16; ++r) {
                        int key = (r & 3) + 8 * (r >> 2) + 4 * hi;
                        int kpos = kbA * BS + key;
                        bool ok = selbit && (kpos <= qpos);
                        pr[r] = ok ? silu_f(accS[r]) : 0.f;
                    }
                } else {
                    #pragma unroll
                    for (int r = 0; r < 16; ++r)
                        pr[r] = selbit ? silu_f(accS[r]) : 0.f;
                }
                uint32_t wv[8];
                #pragma unroll
                for (int i = 0; i < 8; ++i) wv[i] = cvt_pk_bf16(pr[2 * i], pr[2 * i + 1]);
                int2v e0 = __builtin_amdgcn_permlane32_swap(wv[0], wv[2], false, false);
                int2v e1 = __builtin_amdgcn_permlane32_swap(wv[1], wv[3], false, false);
                int2v e2 = __builtin_amdgcn_permlane32_swap(wv[4], wv[6], false, false);
                int2v e3 = __builtin_amdgcn_permlane32_swap(wv[5], wv[7], false, false);
                FragU a0, a1;
                a0.u[0] = e0[0]; a0.u[1] = e1[0]; a0.u[2] = e0[1]; a0.u[3] = e1[1];
                a1.u[0] = e2[0]; a1.u[1] = e3[0]; a1.u[2] = e2[1]; a1.u[3] = e3[1];
                accO0 = __builtin_amdgcn_mfma_f32_32x32x16_bf16(a0.h, bufA.v00.h, accO0, 0, 0, 0);
                accO1 = __builtin_amdgcn_mfma_f32_32x32x16_bf16(a0.h, bufA.v01.h, accO1, 0, 0, 0);
                accO0 = __builtin_amdgcn_mfma_f32_32x32x16_bf16(a1.h, bufA.v10.h, accO0, 0, 0, 0);
                accO1 = __builtin_amdgcn_mfma_f32_32x32x16_bf16(a1.h, bufA.v11.h, accO1, 0, 0, 0);
                if (!haveB) break;
                bufA = bufB; kbA = kbB;
            }
        }

        // ---- gated accumulation ----
        if (any) {
            #pragma unroll
            for (int r = 0; r < 16; ++r) {
                int q = (r & 3) + 8 * (r >> 2) + 4 * hi;
                float gs = gateS[q];
                atomicAdd(&olds[q][l31], gs * accO0[r]);
                atomicAdd(&olds[q][32 + l31], gs * accO1[r]);
            }
        }

        __syncthreads();

        // ---- store (valid tokens only) ----
        {
            int q = tid >> 3, dpart = (tid & 7) * 8;
            int pos = qb * BS + q;
            if (pos < len) {
                float* op = out + (((size_t)(off0 + pos)) * HH + h) * DD + dpart;
                *(float4*)op = *(float4*)&olds[q][dpart];
                *(float4*)(op + 4) = *(float4*)&olds[q][dpart + 4];
            }
        }
    }
}

extern "C" void kernel_launch(void* const* d_in, const int* in_sizes, int n_in,
                              void* d_out, int out_size, void* d_ws, size_t ws_size,
                              hipStream_t stream) {
    const float* pq = (const float*)d_in[4];
    const float* pk = (const float*)d_in[5];
    const float* pv = (const float*)d_in[6];
    const int* xoff = (const int*)d_in[7];
    const float* gw = (const float*)d_in[8];
    float* out = (float*)d_out;

    // ws: Kb 4MB | Vt 4MB | kc 256KB | vct 128KB | cnt 32B
    uint16_t* Kb = (uint16_t*)d_ws;
    uint16_t* Vt = Kb + (size_t)BB * HH * NN * DD;
    float* kc = (float*)(Vt + (size_t)BB * HH * NN * DD);
    uint16_t* vct = (uint16_t*)(kc + (size_t)BB * HH * NB * DD);
    int* cnt = (int*)(vct + (size_t)BB * HH * DD * NB);

    prep_kernel<<<BB * HH * NB, 256, 0, stream>>>(pk, pv, Kb, Vt, kc, vct, cnt);
    bsa_mfma_kernel<<<768, 256, 0, stream>>>(pq, Kb, Vt, kc, vct, gw, xoff, cnt, out);
}

// Round 6
// 182.352 us; speedup vs baseline: 1.0225x; 1.0225x over previous
//
#include <hip/hip_runtime.h>
#include <math.h>
#include <stdint.h>

#define BB 4
#define NN 1024
#define HH 8
#define DD 64
#define BS 32
#define NB 32   // NN/BS
#define SS 16   // BLOCK_COUNTS

typedef __attribute__((ext_vector_type(8)))  short bf16x8;
typedef __attribute__((ext_vector_type(16))) float f32x16;
typedef __attribute__((ext_vector_type(2)))  int   int2v;

union FragU { bf16x8 h; uint32_t u[4]; };

#define ZERO16 {0.f,0.f,0.f,0.f,0.f,0.f,0.f,0.f,0.f,0.f,0.f,0.f,0.f,0.f,0.f,0.f}

__device__ __forceinline__ uint32_t cvt_pk_bf16(float lo, float hi) {
    uint32_t r;
    asm("v_cvt_pk_bf16_f32 %0, %1, %2" : "=v"(r) : "v"(lo), "v"(hi));
    return r;
}

__device__ __forceinline__ uint16_t bf16_rne(float x) {
    uint32_t fb = __float_as_uint(x);
    return (uint16_t)((fb + 0x7fffu + ((fb >> 16) & 1u)) >> 16);
}

__device__ __forceinline__ float silu_f(float x) {
    return __fdividef(x, 1.f + __expf(-x));
}

// Prepass. XCD-ALIGNED with consumer: bid&7 == h, so the XCD that writes a
// head's panels is the XCD that reads them in bsa (cross-XCD L2 bounce was
// the R4/R5 FETCH inflation).
//  Kb : bf16 [b][h][n][d]   K * 0.125 (exact pow2 pre-scale)
//  Vt : bf16 [b][h][d][n]   transposed V
//  kc : f32  [b][h][blk][d] block-mean K * 0.125 (f32-exact selection)
//  vct: bf16 [b][h][d][blk] block-mean V, transposed
__global__ __launch_bounds__(256) void prep_kernel(
    const float* __restrict__ pk, const float* __restrict__ pv,
    uint16_t* __restrict__ Kb, uint16_t* __restrict__ Vt,
    float* __restrict__ kc, uint16_t* __restrict__ vct)
{
    __shared__ float klds[32][65];
    __shared__ float vlds[32][65];
    const int t = threadIdx.x;
    const int h = blockIdx.x & 7;
    const int rest = blockIdx.x >> 3;
    const int blk = rest & 31;
    const int b = rest >> 5;
    const int bh = b * 8 + h;

    const int r = t >> 3;            // token row 0..31
    const int dg = (t & 7) * 8;      // d group
    size_t sbase = (((size_t)(b * NN + blk * BS + r)) * HH + h) * DD + dg;
    float4 ka = *(const float4*)(pk + sbase);
    float4 kb4 = *(const float4*)(pk + sbase + 4);
    float4 va = *(const float4*)(pv + sbase);
    float4 vb4 = *(const float4*)(pv + sbase + 4);

    FragU kf;   // pre-scaled by 0.125 (exact)
    kf.u[0] = cvt_pk_bf16(ka.x * 0.125f, ka.y * 0.125f);
    kf.u[1] = cvt_pk_bf16(ka.z * 0.125f, ka.w * 0.125f);
    kf.u[2] = cvt_pk_bf16(kb4.x * 0.125f, kb4.y * 0.125f);
    kf.u[3] = cvt_pk_bf16(kb4.z * 0.125f, kb4.w * 0.125f);
    *(bf16x8*)(Kb + (((size_t)bh * NN) + blk * BS + r) * DD + dg) = kf.h;

    *(float4*)&klds[r][dg] = ka;  *(float4*)&klds[r][dg + 4] = kb4;
    *(float4*)&vlds[r][dg] = va;  *(float4*)&vlds[r][dg + 4] = vb4;
    __syncthreads();

    if (t < 64) {                    // wave 0: kc (f32 block-mean K, pre-scaled)
        float s = 0.f;
        #pragma unroll
        for (int j = 0; j < 32; ++j) s += klds[j][t];
        kc[((size_t)bh * NB + blk) * DD + t] = s * (0.125f / BS);
    } else if (t < 128) {            // wave 1: vct (bf16 block-mean V, transposed)
        int d = t - 64;
        float s = 0.f;
        #pragma unroll
        for (int j = 0; j < 32; ++j) s += vlds[j][d];
        vct[((size_t)bh * DD + d) * NB + blk] = bf16_rne(s * (1.f / BS));
    }

    // all threads: V transpose -> Vt
    {
        int d = t >> 2, ng = (t & 3) * 8;
        float p0 = vlds[ng + 0][d], p1 = vlds[ng + 1][d];
        float p2 = vlds[ng + 2][d], p3 = vlds[ng + 3][d];
        float p4 = vlds[ng + 4][d], p5 = vlds[ng + 5][d];
        float p6 = vlds[ng + 6][d], p7 = vlds[ng + 7][d];
        FragU vf;
        vf.u[0] = cvt_pk_bf16(p0, p1); vf.u[1] = cvt_pk_bf16(p2, p3);
        vf.u[2] = cvt_pk_bf16(p4, p5); vf.u[3] = cvt_pk_bf16(p6, p7);
        *(bf16x8*)(Vt + ((size_t)bh * DD + d) * NN + blk * BS + ng) = vf.h;
    }
}

__device__ __forceinline__ void load_k(FragU* K, const uint16_t* __restrict__ Kb,
                                       int bh, int kb, int l31, int hi)
{
    const uint16_t* krow = Kb + (((size_t)bh * NN) + kb * BS + l31) * DD + hi * 8;
    K[0].h = *(const bf16x8*)(krow);
    K[1].h = *(const bf16x8*)(krow + 16);
    K[2].h = *(const bf16x8*)(krow + 32);
    K[3].h = *(const bf16x8*)(krow + 48);
}

// Static schedule: h = bid&7 (== XCD under round-robin dispatch); within an
// XCD, tiles ordered qb-descending with b round-robin -> exact XCD balance,
// heavy-first CU backfill, light tail.
__global__ __launch_bounds__(256, 4) void bsa_mfma_kernel(
    const float* __restrict__ pq, const uint16_t* __restrict__ Kb,
    const uint16_t* __restrict__ Vt, const float* __restrict__ kc,
    const uint16_t* __restrict__ vct, const float* __restrict__ gw,
    const int* __restrict__ xoff, float* __restrict__ out)
{
    __shared__ float qlds[32][64];
    __shared__ __align__(16) uint16_t pcmp[32][40];
    __shared__ uint32_t selmask[32];
    __shared__ float gateC[32], gateS[32];
    __shared__ float olds[32][64];

    const int tid = threadIdx.x;
    const int lane = tid & 63;
    const int w = tid >> 6;
    const int l31 = lane & 31;
    const int hi = lane >> 5;

    const int h = blockIdx.x & 7;
    const int j = blockIdx.x >> 3;       // 0..127 within XCD
    const int qb = 31 - (j >> 2);        // heavy-first
    const int b = j & 3;                 // b round-robin
    const int bh = b * 8 + h;

    const int off0 = xoff[b];
    const int len = xoff[b + 1] - off0;
    if (qb * BS >= len) return;          // padded tile (uniform exit)

    // ---- zero slab + load Q tile ----
    {
        int q = tid >> 3, d = (tid & 7) * 8;
        *(float4*)&olds[q][d] = make_float4(0.f, 0.f, 0.f, 0.f);
        *(float4*)&olds[q][d + 4] = make_float4(0.f, 0.f, 0.f, 0.f);
        const float* src = pq + (((size_t)(b * NN + qb * BS + q)) * HH + h) * DD + d;
        *(float4*)&qlds[q][d] = *(const float4*)src;
        *(float4*)&qlds[q][d + 4] = *(const float4*)(src + 4);
    }

    // ---- Q B-fragments (bf16, unscaled) ----
    FragU qf[4];
    {
        const float* qrow = pq + (((size_t)(b * NN + qb * BS + l31)) * HH + h) * DD;
        #pragma unroll
        for (int t = 0; t < 4; ++t) {
            const float* qp = qrow + t * 16 + hi * 8;
            float4 x = *(const float4*)qp;
            float4 y = *(const float4*)(qp + 4);
            qf[t].u[0] = cvt_pk_bf16(x.x, x.y);
            qf[t].u[1] = cvt_pk_bf16(x.z, x.w);
            qf[t].u[2] = cvt_pk_bf16(y.x, y.y);
            qf[t].u[3] = cvt_pk_bf16(y.z, y.w);
        }
    }

    // ---- compressed-K fragments (pre-scaled) + gate weights ----
    float4 kcv[8];
    {
        const float* kcrow = kc + ((size_t)bh * NB + l31) * DD + hi * 32;
        #pragma unroll
        for (int i = 0; i < 8; ++i) kcv[i] = *(const float4*)(kcrow + i * 4);
    }
    const float gwc = gw[(h * DD + lane) * 3 + 0];
    const float gws = gw[(h * DD + lane) * 3 + 1];

    __syncthreads();   // qlds + olds ready

    // ---- selection + gates: wave w -> queries w*8..w*8+7 ----
    for (int jq = 0; jq < 8; ++jq) {
        int q = w * 8 + jq;
        const float* qv = qlds[q];
        const float* qh = qv + hi * 32;
        float part = 0.f;
        #pragma unroll
        for (int i = 0; i < 8; ++i) {
            float4 qq = *(const float4*)(qh + i * 4);
            part += qq.x * kcv[i].x + qq.y * kcv[i].y + qq.z * kcv[i].z + qq.w * kcv[i].w;
        }
        float s = part + __shfl_xor(part, 32);       // already scaled
        float p = (l31 <= qb) ? silu_f(s) : 0.f;
        if (lane < 32) pcmp[q][l31] = bf16_rne(p);
        uint32_t m;
        if (qb >= SS) {
            float vsel = (l31 <= qb) ? s : -INFINITY;
            int rank = 0;
            #pragma unroll
            for (int off = 1; off < 32; ++off) {
                float o = __shfl_xor(vsel, off);
                int oi = l31 ^ off;
                rank += (o > vsel || (o == vsel && oi < l31)) ? 1 : 0;
            }
            m = (uint32_t)(__ballot(rank < SS) & 0xffffffffu);
        } else {
            m = (1u << (qb + 1)) - 1u;
        }
        if (lane == 0) selmask[q] = m;
        float qd = qv[lane];
        float g0 = qd * gwc;
        float g1 = qd * gws;
        #pragma unroll
        for (int off = 32; off; off >>= 1) {
            g0 += __shfl_xor(g0, off);
            g1 += __shfl_xor(g1, off);
        }
        if (lane == 0) {
            gateC[q] = __frcp_rn(1.f + __expf(-g0));
            gateS[q] = __frcp_rn(1.f + __expf(-g1));
        }
    }

    __syncthreads();   // pcmp, selmask, gates ready

    const uint32_t mymask = selmask[l31];
    uint32_t tmask = mymask;
    #pragma unroll
    for (int off = 1; off < 32; off <<= 1) tmask |= __shfl_xor(tmask, off);

    // ---- wave 3: compressed branch (gated) ----
    if (w == 3) {
        f32x16 c0 = ZERO16, c1 = ZERO16;
        #pragma unroll
        for (int s = 0; s < 2; ++s) {
            FragU pa;
            pa.h = *(const bf16x8*)&pcmp[l31][s * 16 + hi * 8];
            #pragma unroll
            for (int dh = 0; dh < 2; ++dh) {
                FragU vb;
                vb.h = *(const bf16x8*)(vct + ((size_t)bh * DD + dh * 32 + l31) * NB + s * 16 + hi * 8);
                if (dh == 0) c0 = __builtin_amdgcn_mfma_f32_32x32x16_bf16(pa.h, vb.h, c0, 0, 0, 0);
                else         c1 = __builtin_amdgcn_mfma_f32_32x32x16_bf16(pa.h, vb.h, c1, 0, 0, 0);
            }
        }
        #pragma unroll
        for (int r = 0; r < 16; ++r) {
            int q = (r & 3) + 8 * (r >> 2) + 4 * hi;
            float gc = gateC[q];
            atomicAdd(&olds[q][l31], gc * c0[r]);
            atomicAdd(&olds[q][32 + l31], gc * c1[r]);
        }
    }

    // ---- this wave's key blocks (round-robin over union set bits) ----
    uint32_t mw = 0;
    {
        uint32_t m = tmask; int c = 0;
        while (m) {
            int kb = __builtin_ctz(m); m &= m - 1;
            if (((c++) & 3) == w) mw |= (1u << kb);
        }
    }

    f32x16 accO0 = ZERO16, accO1 = ZERO16;
    const bool any = (mw != 0);
    const int qpos = qb * BS + l31;

    // one key-block compute step (V loaded inside; latency overlaps silu)
    #define COMPUTE_BLOCK(KBUF, KBIDX)                                          \
    {                                                                           \
        const int kbc = (KBIDX);                                                \
        f32x16 accS = ZERO16;                                                   \
        accS = __builtin_amdgcn_mfma_f32_32x32x16_bf16(KBUF[0].h, qf[0].h, accS, 0, 0, 0); \
        accS = __builtin_amdgcn_mfma_f32_32x32x16_bf16(KBUF[1].h, qf[1].h, accS, 0, 0, 0); \
        accS = __builtin_amdgcn_mfma_f32_32x32x16_bf16(KBUF[2].h, qf[2].h, accS, 0, 0, 0); \
        accS = __builtin_amdgcn_mfma_f32_32x32x16_bf16(KBUF[3].h, qf[3].h, accS, 0, 0, 0); \
        const uint16_t* vrow = Vt + ((size_t)bh * DD + l31) * NN + kbc * BS + hi * 8; \
        FragU v00, v10, v01, v11;                                               \
        v00.h = *(const bf16x8*)(vrow);                                         \
        v10.h = *(const bf16x8*)(vrow + 16);                                    \
        v01.h = *(const bf16x8*)(vrow + 32 * NN);                               \
        v11.h = *(const bf16x8*)(vrow + 32 * NN + 16);                          \
        const bool selbit = (mymask >> kbc) & 1;                                \
        float pr[16];                                                           \
        if (kbc == qb) {                                                        \
            _Pragma("unroll")                                                   \
            for (int r = 0; r < 16; ++r) {                                      \
                int key = (r & 3) + 8 * (r >> 2) + 4 * hi;                      \
                bool ok = selbit && (kbc * BS + key <= qpos);                   \
                pr[r] = ok ? silu_f(accS[r]) : 0.f;                             \
            }                                                                   \
        } else {                                                                \
            _Pragma("unroll")                                                   \
            for (int r = 0; r < 16; ++r)                                        \
                pr[r] = selbit ? silu_f(accS[r]) : 0.f;                         \
        }                                                                       \
        uint32_t wv[8];                                                         \
        _Pragma("unroll")                                                       \
        for (int i = 0; i < 8; ++i) wv[i] = cvt_pk_bf16(pr[2 * i], pr[2 * i + 1]); \
        int2v e0 = __builtin_amdgcn_permlane32_swap(wv[0], wv[2], false, false); \
        int2v e1 = __builtin_amdgcn_permlane32_swap(wv[1], wv[3], false, false); \
        int2v e2 = __builtin_amdgcn_permlane32_swap(wv[4], wv[6], false, false); \
        int2v e3 = __builtin_amdgcn_permlane32_swap(wv[5], wv[7], false, false); \
        FragU a0, a1;                                                           \
        a0.u[0] = e0[0]; a0.u[1] = e1[0]; a0.u[2] = e0[1]; a0.u[3] = e1[1];     \
        a1.u[0] = e2[0]; a1.u[1] = e3[0]; a1.u[2] = e2[1]; a1.u[3] = e3[1];     \
        accO0 = __builtin_amdgcn_mfma_f32_32x32x16_bf16(a0.h, v00.h, accO0, 0, 0, 0); \
        accO1 = __builtin_amdgcn_mfma_f32_32x32x16_bf16(a0.h, v01.h, accO1, 0, 0, 0); \
        accO0 = __builtin_amdgcn_mfma_f32_32x32x16_bf16(a1.h, v10.h, accO0, 0, 0, 0); \
        accO1 = __builtin_amdgcn_mfma_f32_32x32x16_bf16(a1.h, v11.h, accO1, 0, 0, 0); \
    }

    if (any) {
        // copy-free ping-pong: prefetch next K while computing current
        FragU KA[4], KB[4];
        int kbA = __builtin_ctz(mw);
        uint32_t rem = mw & (mw - 1);
        load_k(KA, Kb, bh, kbA, l31, hi);
        for (;;) {
            bool hasB = (rem != 0); int kbB = 0;
            if (hasB) { kbB = __builtin_ctz(rem); rem &= rem - 1; load_k(KB, Kb, bh, kbB, l31, hi); }
            COMPUTE_BLOCK(KA, kbA);
            if (!hasB) break;
            bool hasA = (rem != 0);
            if (hasA) { kbA = __builtin_ctz(rem); rem &= rem - 1; load_k(KA, Kb, bh, kbA, l31, hi); }
            COMPUTE_BLOCK(KB, kbB);
            if (!hasA) break;
        }
        // gated accumulation
        #pragma unroll
        for (int r = 0; r < 16; ++r) {
            int q = (r & 3) + 8 * (r >> 2) + 4 * hi;
            float gs = gateS[q];
            atomicAdd(&olds[q][l31], gs * accO0[r]);
            atomicAdd(&olds[q][32 + l31], gs * accO1[r]);
        }
    }
    #undef COMPUTE_BLOCK

    __syncthreads();

    // ---- store (valid tokens only) ----
    {
        int q = tid >> 3, dpart = (tid & 7) * 8;
        int pos = qb * BS + q;
        if (pos < len) {
            float* op = out + (((size_t)(off0 + pos)) * HH + h) * DD + dpart;
            *(float4*)op = *(float4*)&olds[q][dpart];
            *(float4*)(op + 4) = *(float4*)&olds[q][dpart + 4];
        }
    }
}

extern "C" void kernel_launch(void* const* d_in, const int* in_sizes, int n_in,
                              void* d_out, int out_size, void* d_ws, size_t ws_size,
                              hipStream_t stream) {
    const float* pq = (const float*)d_in[4];
    const float* pk = (const float*)d_in[5];
    const float* pv = (const float*)d_in[6];
    const int* xoff = (const int*)d_in[7];
    const float* gw = (const float*)d_in[8];
    float* out = (float*)d_out;

    // ws: Kb 4MB | Vt 4MB | kc 256KB | vct 128KB
    uint16_t* Kb = (uint16_t*)d_ws;
    uint16_t* Vt = Kb + (size_t)BB * HH * NN * DD;
    float* kc = (float*)(Vt + (size_t)BB * HH * NN * DD);
    uint16_t* vct = (uint16_t*)(kc + (size_t)BB * HH * NB * DD);

    prep_kernel<<<BB * HH * NB, 256, 0, stream>>>(pk, pv, Kb, Vt, kc, vct);
    bsa_mfma_kernel<<<BB * HH * NB, 256, 0, stream>>>(pq, Kb, Vt, kc, vct, gw, xoff, out);
}